// Round 9
// baseline (233.625 us; speedup 1.0000x reference)
//
#include <hip/hip_runtime.h>
#include <cstdint>
#include <cstddef>

// Problem constants
#define NB    8192      // batch
#define NP    4849      // params per item
#define NW    48        // target net width

// Tiled intermediate layout (round-9): Pp is stored as [chunk][i][cw] where
// chunk = rp>>7 (38 chunks of 128 params), cw = rp&127.
//   addr(i, rp) = ((rp>>7)*NB + i)*128 + (rp&127)
// GEMM block (rp0=bx*128) writes, per item-row, 128 consecutive floats at
// ((bx*NB+i)*128) -> 64 items x 512 B CONTIGUOUS per block (32 KB), fixing
// the scattered-64B-writeback pattern that pinned all prior GEMM variants at
// ~1.5 TB/s effective write BW. Adam reads stay coalesced: every dwordx4 is
// 4-aligned in rp so it never crosses a 128-float chunk.
#define NCH   38        // ceil(NP/128)

typedef __attribute__((ext_vector_type(8))) _Float16 f16x8;
typedef __attribute__((ext_vector_type(4))) float f32x4;
typedef __attribute__((ext_vector_type(2))) float f32x2;

__device__ __forceinline__ const float* pptr(const float* Pp, int i, int rp) {
  return Pp + ((size_t)(rp >> 7) * NB + i) * 128 + (rp & 127);
}

// ---------------------------------------------------------------------------
// Parameter permutation (unchanged): Pp stores P_orig[i][invperm(rp)] at
// logical index rp, so adam (lane j owns row j) loads w1/w2 with dwordx4.
// ---------------------------------------------------------------------------
__device__ __forceinline__ int invperm(int rp) {
  if (rp >= 96 && rp < 2400) {
    int t = rp - 96; int kb = t / 192; int rem = t - kb * 192;
    return 96 + (rem >> 2) * 48 + (kb * 4 + (rem & 3));
  }
  if (rp >= 2448 && rp < 4752) {
    int t = rp - 2448; int kb = t / 192; int rem = t - kb * 192;
    return 2448 + (rem >> 2) * 48 + (kb * 4 + (rem & 3));
  }
  return rp;
}

// ---------------------------------------------------------------------------
// Kernel 1: split-fp16 MFMA GEMM, 64(M) x 128(N), no LDS / no barrier.
// Compute identical to R6/R8 (known-good ~105 us); ONLY the store addressing
// changed to the tiled layout (contiguous 32 KB per block).
// ---------------------------------------------------------------------------
__global__ __launch_bounds__(256, 2) void hyper_gemm(
    const float* __restrict__ x, const float* __restrict__ c,
    const float* __restrict__ hw1, const float* __restrict__ hb1,
    const float* __restrict__ hw2, const float* __restrict__ hb2,
    float* __restrict__ Pp)
{
  const int t   = threadIdx.x;
  const int i0  = blockIdx.y * 64;
  const int rp0 = blockIdx.x * 128;

  const int lane = t & 63;
  const int wv   = t >> 6;
  const int m16  = lane & 15;
  const int q    = lane >> 4;

  float xv[4], cv[4];
  #pragma unroll
  for (int mt = 0; mt < 4; ++mt) {
    int i = i0 + mt * 16 + m16;
    xv[mt] = x[i]; cv[mt] = c[i];
  }

  const float* wr[2];
  #pragma unroll
  for (int nt = 0; nt < 2; ++nt) {
    int rp = rp0 + wv * 32 + nt * 16 + m16;
    wr[nt] = hw2 + (size_t)(rp < NP ? invperm(rp) : 0) * 96;
  }

  f32x4 acc[4][2];
  #pragma unroll
  for (int mt = 0; mt < 4; ++mt)
    #pragma unroll
    for (int nt = 0; nt < 2; ++nt)
      acc[mt][nt] = (f32x4){0.f, 0.f, 0.f, 0.f};

  #pragma unroll
  for (int ch = 0; ch < 3; ++ch) {
    const int k0 = ch * 32 + q * 8;

    float4 bf0[2], bf1[2];
    #pragma unroll
    for (int nt = 0; nt < 2; ++nt) {
      bf0[nt] = *(const float4*)(wr[nt] + k0);
      bf1[nt] = *(const float4*)(wr[nt] + k0 + 4);
    }

    float4 A0 = *(const float4*)(hw1 + 2 * k0);
    float4 A1 = *(const float4*)(hw1 + 2 * k0 + 4);
    float4 A2 = *(const float4*)(hw1 + 2 * k0 + 8);
    float4 A3 = *(const float4*)(hw1 + 2 * k0 + 12);
    float4 B0 = *(const float4*)(hb1 + k0);
    float4 B1 = *(const float4*)(hb1 + k0 + 4);
    float w0k[8] = {A0.x,A0.z,A1.x,A1.z,A2.x,A2.z,A3.x,A3.z};
    float w1k[8] = {A0.y,A0.w,A1.y,A1.w,A2.y,A2.w,A3.y,A3.w};
    float bk[8]  = {B0.x,B0.y,B0.z,B0.w,B1.x,B1.y,B1.z,B1.w};

    f16x8 ah[4], al[4];
    #pragma unroll
    for (int mt = 0; mt < 4; ++mt) {
      #pragma unroll
      for (int j = 0; j < 8; ++j) {
        float h = fmaf(xv[mt], w0k[j], fmaf(cv[mt], w1k[j], bk[j]));
        h = h > 0.f ? h : 0.f;
        _Float16 hi = (_Float16)h;
        float r = h - (float)hi;
        ah[mt][j] = hi;
        al[mt][j] = (_Float16)r;
      }
    }

    f16x8 bh[2], bl[2];
    #pragma unroll
    for (int nt = 0; nt < 2; ++nt) {
      float fv[8] = {bf0[nt].x,bf0[nt].y,bf0[nt].z,bf0[nt].w,
                     bf1[nt].x,bf1[nt].y,bf1[nt].z,bf1[nt].w};
      #pragma unroll
      for (int e = 0; e < 8; ++e) {
        _Float16 hi = (_Float16)fv[e];
        float r = fv[e] - (float)hi;
        bh[nt][e] = hi;
        bl[nt][e] = (_Float16)r;
      }
    }

    #pragma unroll
    for (int mt = 0; mt < 4; ++mt)
      #pragma unroll
      for (int nt = 0; nt < 2; ++nt) {
        acc[mt][nt] = __builtin_amdgcn_mfma_f32_16x16x32_f16(al[mt], bl[nt], acc[mt][nt], 0, 0, 0);
        acc[mt][nt] = __builtin_amdgcn_mfma_f32_16x16x32_f16(ah[mt], bl[nt], acc[mt][nt], 0, 0, 0);
        acc[mt][nt] = __builtin_amdgcn_mfma_f32_16x16x32_f16(al[mt], bh[nt], acc[mt][nt], 0, 0, 0);
        acc[mt][nt] = __builtin_amdgcn_mfma_f32_16x16x32_f16(ah[mt], bh[nt], acc[mt][nt], 0, 0, 0);
      }
  }

  // ---- epilogue: bias + TILED store (chunk = blockIdx.x) ----
  float* cbase = Pp + (size_t)blockIdx.x * NB * 128;
  #pragma unroll
  for (int nt = 0; nt < 2; ++nt) {
    int off = wv * 32 + nt * 16 + m16;        // rp - rp0, always < 128
    int rp  = rp0 + off;
    if (rp < NP) {
      float bias = hb2[invperm(rp)];
      #pragma unroll
      for (int mt = 0; mt < 4; ++mt)
        #pragma unroll
        for (int r = 0; r < 4; ++r) {
          int i = i0 + mt * 16 + q * 4 + r;
          cbase[(size_t)i * 128 + off] = acc[mt][nt][r] + bias;
        }
    }
  }
}

// ---------------------------------------------------------------------------
// Kernel 2: per-item 20-step Adam on g = f'(y).  Math identical to R8
// (pk_fma + LDS broadcast).  R9 change: launch_bounds(256,3) -> reg cap 170,
// enough for weights(96)+state(~60) without scratch spill (R7's cap-128
// disaster), targeting 3 waves/SIMD vs R8's 2.
// ---------------------------------------------------------------------------
__device__ __forceinline__ float rcp_nr(float d) {
  float r = __builtin_amdgcn_rcpf(d);
  return fmaf(-d, r, 2.f) * r;
}

__global__ __launch_bounds__(256, 3) void adam_inner(
    const float* __restrict__ Pp, float* __restrict__ out)
{
  __shared__ __align__(16) float hd[4][2][96];   // [wave][buf][h(48)|dh(48)]

  const int lane = threadIdx.x & 63;
  const int wv   = threadIdx.x >> 6;
  const int i    = blockIdx.x * 4 + wv;
  const bool act = lane < NW;

  float* buf0 = &hd[wv][0][0];
  float* buf1 = &hd[wv][1][0];

  float w0  = act ? *pptr(Pp, i, lane)        : 0.f;
  float b0  = act ? *pptr(Pp, i, 48 + lane)   : 0.f;
  float b1v = act ? *pptr(Pp, i, 2400 + lane) : 0.f;
  float b2v = act ? *pptr(Pp, i, 4752 + lane) : 0.f;
  float w3  = act ? *pptr(Pp, i, 4800 + lane) : 0.f;

  // weights as f32x2 pairs (dwordx4 loads; 4-aligned rp never crosses chunk)
  f32x2 w1p[24], w2p[24];
  #pragma unroll
  for (int kb = 0; kb < 12; ++kb) {
    float4 q1 = *(const float4*)pptr(Pp, i, 96 + kb * 192 + lane * 4);
    w1p[2 * kb]     = (f32x2){q1.x, q1.y};
    w1p[2 * kb + 1] = (f32x2){q1.z, q1.w};
    float4 q2 = *(const float4*)pptr(Pp, i, 2448 + kb * 192 + lane * 4);
    w2p[2 * kb]     = (f32x2){q2.x, q2.y};
    w2p[2 * kb + 1] = (f32x2){q2.z, q2.w};
  }

  float y = 0.f, m = 0.f, v = 0.f;
  float b1t = 1.f, b2t = 1.f;

  #pragma unroll 1
  for (int t = 0; t < 20; ++t) {
    // ---- layer 0 (scalar input): lane j computes unit j ----
    float z  = fmaf(w0, y, b0);
    float e  = fminf(__expf(-z), 8.0e37f);
    float s  = rcp_nr(1.f + e);
    float h  = z * s;
    float dh = fmaf(z * s, 1.f - s, s) * w0;
    if (act) { buf0[lane] = h; buf0[48 + lane] = dh; }

    // ---- layer 1: packed even/odd-k partials ----
    f32x2 zz1a = (f32x2){b1v, 0.f}, zz1b = (f32x2){0.f, 0.f};
    f32x2 dd1a = (f32x2){0.f, 0.f}, dd1b = (f32x2){0.f, 0.f};
    #pragma unroll
    for (int kk = 0; kk < 12; ++kk) {
      float4 ph = *(const float4*)(buf0 + 4 * kk);
      float4 pd = *(const float4*)(buf0 + 48 + 4 * kk);
      zz1a = __builtin_elementwise_fma(w1p[2 * kk],     (f32x2){ph.x, ph.y}, zz1a);
      zz1b = __builtin_elementwise_fma(w1p[2 * kk + 1], (f32x2){ph.z, ph.w}, zz1b);
      dd1a = __builtin_elementwise_fma(w1p[2 * kk],     (f32x2){pd.x, pd.y}, dd1a);
      dd1b = __builtin_elementwise_fma(w1p[2 * kk + 1], (f32x2){pd.z, pd.w}, dd1b);
    }
    float z1  = (zz1a.x + zz1a.y) + (zz1b.x + zz1b.y);
    float dz1 = (dd1a.x + dd1a.y) + (dd1b.x + dd1b.y);

    e  = fminf(__expf(-z1), 8.0e37f);
    s  = rcp_nr(1.f + e);
    h  = z1 * s;
    dh = fmaf(z1 * s, 1.f - s, s) * dz1;
    if (act) { buf1[lane] = h; buf1[48 + lane] = dh; }

    // ---- layer 2 ----
    f32x2 zz2a = (f32x2){b2v, 0.f}, zz2b = (f32x2){0.f, 0.f};
    f32x2 dd2a = (f32x2){0.f, 0.f}, dd2b = (f32x2){0.f, 0.f};
    #pragma unroll
    for (int kk = 0; kk < 12; ++kk) {
      float4 ph = *(const float4*)(buf1 + 4 * kk);
      float4 pd = *(const float4*)(buf1 + 48 + 4 * kk);
      zz2a = __builtin_elementwise_fma(w2p[2 * kk],     (f32x2){ph.x, ph.y}, zz2a);
      zz2b = __builtin_elementwise_fma(w2p[2 * kk + 1], (f32x2){ph.z, ph.w}, zz2b);
      dd2a = __builtin_elementwise_fma(w2p[2 * kk],     (f32x2){pd.x, pd.y}, dd2a);
      dd2b = __builtin_elementwise_fma(w2p[2 * kk + 1], (f32x2){pd.z, pd.w}, dd2b);
    }
    float z2  = (zz2a.x + zz2a.y) + (zz2b.x + zz2b.y);
    float dz2 = (dd2a.x + dd2a.y) + (dd2b.x + dd2b.y);

    e  = fminf(__expf(-z2), 8.0e37f);
    s  = rcp_nr(1.f + e);
    dh = fmaf(z2 * s, 1.f - s, s) * dz2;

    // ---- g = w3 . dh3 (butterfly reduce) ----
    float tg = act ? w3 * dh : 0.f;
    #pragma unroll
    for (int off = 1; off < 64; off <<= 1) tg += __shfl_xor(tg, off, 64);
    float g = tg;

    // ---- Adam update (replicated per lane) ----
    m = fmaf(0.9f,   m, 0.1f   * g);
    v = fmaf(0.999f, v, 0.001f * g * g);
    b1t *= 0.9f; b2t *= 0.999f;
    float mh  = m * rcp_nr(1.f - b1t);
    float vh  = v * rcp_nr(1.f - b2t);
    float den = __builtin_amdgcn_sqrtf(vh) + 1e-8f;
    y -= 0.1f * mh * rcp_nr(den);
  }

  if (lane == 0) out[i] = y;
}

// ---------------------------------------------------------------------------
extern "C" void kernel_launch(void* const* d_in, const int* in_sizes, int n_in,
                              void* d_out, int out_size, void* d_ws, size_t ws_size,
                              hipStream_t stream) {
  const float* x   = (const float*)d_in[0];
  const float* c   = (const float*)d_in[1];
  const float* hw1 = (const float*)d_in[2];
  const float* hb1 = (const float*)d_in[3];
  const float* hw2 = (const float*)d_in[4];
  const float* hb2 = (const float*)d_in[5];
  float* Pp  = (float*)d_ws;   // NCH*NB*128*4 = 159,383,552 bytes
  float* out = (float*)d_out;

  dim3 gridB(38, 128);         // ceil(4849/128) x (8192/64)
  hyper_gemm<<<gridB, dim3(256), 0, stream>>>(x, c, hw1, hb1, hw2, hb2, Pp);
  adam_inner<<<dim3(2048), dim3(256), 0, stream>>>(Pp, out);
}

// Round 10
// 228.442 us; speedup vs baseline: 1.0227x; 1.0227x over previous
//
#include <hip/hip_runtime.h>
#include <cstdint>
#include <cstddef>

// Problem constants
#define NB    8192      // batch
#define NP    4849      // params per item
#define NW    48        // target net width
#define NCH   38        // ceil(NP/128)
#define GY    16        // persistent-gemm grid y; each block does 128/GY = 8 M-tiles

// Tiled intermediate layout (kept from R9, neutral for gemm, fine for adam):
//   addr(i, rp) = ((rp>>7)*NB + i)*128 + (rp&127)
typedef __attribute__((ext_vector_type(8))) _Float16 f16x8;
typedef __attribute__((ext_vector_type(4))) float f32x4;
typedef __attribute__((ext_vector_type(2))) float f32x2;

__device__ __forceinline__ const float* pptr(const float* Pp, int i, int rp) {
  return Pp + ((size_t)(rp >> 7) * NB + i) * 128 + (rp & 127);
}

// ---------------------------------------------------------------------------
// Parameter permutation (unchanged): Pp stores P_orig[i][invperm(rp)] at
// logical index rp, so adam (lane j owns row j) loads w1/w2 with dwordx4.
// ---------------------------------------------------------------------------
__device__ __forceinline__ int invperm(int rp) {
  if (rp >= 96 && rp < 2400) {
    int t = rp - 96; int kb = t / 192; int rem = t - kb * 192;
    return 96 + (rem >> 2) * 48 + (kb * 4 + (rem & 3));
  }
  if (rp >= 2448 && rp < 4752) {
    int t = rp - 2448; int kb = t / 192; int rem = t - kb * 192;
    return 2448 + (rem >> 2) * 48 + (kb * 4 + (rem & 3));
  }
  return rp;
}

// ---------------------------------------------------------------------------
// Kernel 1 (R10): PERSISTENT split-fp16 MFMA GEMM.
// Grid 38 x 16. Each block owns one 128-param n-chunk, loads + split-converts
// its B fragments ONCE into registers (f16 hi/lo, ~48 VGPRs), then
// grid-strides over 8 M-tiles of 64 items. This removes the per-block
// B-gather (12 scatter float4s x ~32 lines @ L2 latency) that all five prior
// variants paid 4864x — the one shared property of the 105-110 us plateau.
// ---------------------------------------------------------------------------
__global__ __launch_bounds__(256, 2) void hyper_gemm(
    const float* __restrict__ x, const float* __restrict__ c,
    const float* __restrict__ hw1, const float* __restrict__ hb1,
    const float* __restrict__ hw2, const float* __restrict__ hb2,
    float* __restrict__ Pp)
{
  const int t    = threadIdx.x;
  const int lane = t & 63;
  const int wv   = t >> 6;
  const int m16  = lane & 15;
  const int q    = lane >> 4;
  const int rp0  = blockIdx.x * 128;

  // ---- load + split-convert B ONCE (resident for all M-tiles) ----
  const float* wr[2];
  float bias[2];
  #pragma unroll
  for (int nt = 0; nt < 2; ++nt) {
    int rp = rp0 + wv * 32 + nt * 16 + m16;
    int r  = (rp < NP) ? invperm(rp) : 0;
    wr[nt]   = hw2 + (size_t)r * 96;
    bias[nt] = (rp < NP) ? hb2[r] : 0.f;
  }

  f16x8 bh[3][2], bl[3][2];
  #pragma unroll
  for (int ch = 0; ch < 3; ++ch) {
    const int k0 = ch * 32 + q * 8;
    #pragma unroll
    for (int nt = 0; nt < 2; ++nt) {
      float4 f0 = *(const float4*)(wr[nt] + k0);
      float4 f1 = *(const float4*)(wr[nt] + k0 + 4);
      float fv[8] = {f0.x,f0.y,f0.z,f0.w,f1.x,f1.y,f1.z,f1.w};
      #pragma unroll
      for (int e = 0; e < 8; ++e) {
        _Float16 hi = (_Float16)fv[e];
        float r = fv[e] - (float)hi;
        bh[ch][nt][e] = hi;
        bl[ch][nt][e] = (_Float16)r;
      }
    }
  }

  float* cbase = Pp + (size_t)blockIdx.x * NB * 128;

  // ---- grid-stride over M-tiles ----
  for (int mtile = blockIdx.y; mtile < 128; mtile += GY) {
    const int i0 = mtile * 64;

    float xv[4], cv[4];
    #pragma unroll
    for (int mt = 0; mt < 4; ++mt) {
      int i = i0 + mt * 16 + m16;
      xv[mt] = x[i]; cv[mt] = c[i];
    }

    f32x4 acc[4][2];
    #pragma unroll
    for (int mt = 0; mt < 4; ++mt)
      #pragma unroll
      for (int nt = 0; nt < 2; ++nt)
        acc[mt][nt] = (f32x4){0.f, 0.f, 0.f, 0.f};

    #pragma unroll
    for (int ch = 0; ch < 3; ++ch) {
      const int k0 = ch * 32 + q * 8;

      // hw1/hb1 coefficients (quad-uniform, L1-hot; reloaded to save VGPRs)
      float4 A0 = *(const float4*)(hw1 + 2 * k0);
      float4 A1 = *(const float4*)(hw1 + 2 * k0 + 4);
      float4 A2 = *(const float4*)(hw1 + 2 * k0 + 8);
      float4 A3 = *(const float4*)(hw1 + 2 * k0 + 12);
      float4 B0 = *(const float4*)(hb1 + k0);
      float4 B1 = *(const float4*)(hb1 + k0 + 4);
      float w0k[8] = {A0.x,A0.z,A1.x,A1.z,A2.x,A2.z,A3.x,A3.z};
      float w1k[8] = {A0.y,A0.w,A1.y,A1.w,A2.y,A2.w,A3.y,A3.w};
      float bk[8]  = {B0.x,B0.y,B0.z,B0.w,B1.x,B1.y,B1.z,B1.w};

      f16x8 ah[4], al[4];
      #pragma unroll
      for (int mt = 0; mt < 4; ++mt) {
        #pragma unroll
        for (int j = 0; j < 8; ++j) {
          float h = fmaf(xv[mt], w0k[j], fmaf(cv[mt], w1k[j], bk[j]));
          h = h > 0.f ? h : 0.f;
          _Float16 hi = (_Float16)h;
          float r = h - (float)hi;
          ah[mt][j] = hi;
          al[mt][j] = (_Float16)r;
        }
      }

      #pragma unroll
      for (int mt = 0; mt < 4; ++mt)
        #pragma unroll
        for (int nt = 0; nt < 2; ++nt) {
          acc[mt][nt] = __builtin_amdgcn_mfma_f32_16x16x32_f16(al[mt], bl[ch][nt], acc[mt][nt], 0, 0, 0);
          acc[mt][nt] = __builtin_amdgcn_mfma_f32_16x16x32_f16(ah[mt], bl[ch][nt], acc[mt][nt], 0, 0, 0);
          acc[mt][nt] = __builtin_amdgcn_mfma_f32_16x16x32_f16(al[mt], bh[ch][nt], acc[mt][nt], 0, 0, 0);
          acc[mt][nt] = __builtin_amdgcn_mfma_f32_16x16x32_f16(ah[mt], bh[ch][nt], acc[mt][nt], 0, 0, 0);
        }
    }

    // ---- epilogue: bias + tiled store (contiguous 32 KB per tile) ----
    #pragma unroll
    for (int nt = 0; nt < 2; ++nt) {
      int off = wv * 32 + nt * 16 + m16;
      if (rp0 + off < NP) {
        #pragma unroll
        for (int mt = 0; mt < 4; ++mt)
          #pragma unroll
          for (int r = 0; r < 4; ++r) {
            int i = i0 + mt * 16 + q * 4 + r;
            cbase[(size_t)i * 128 + off] = acc[mt][nt][r] + bias[nt];
          }
      }
    }
  }
}

// ---------------------------------------------------------------------------
// Kernel 2: per-item 20-step Adam on g = f'(y).  EXACT R8 configuration
// (launch_bounds(256,2), pk_fma, LDS broadcast) — R9's (256,3) caused ~8.7MB
// scratch spill and regressed 118->126. Only the Pp addressing is tiled.
// ---------------------------------------------------------------------------
__device__ __forceinline__ float rcp_nr(float d) {
  float r = __builtin_amdgcn_rcpf(d);
  return fmaf(-d, r, 2.f) * r;
}

__global__ __launch_bounds__(256, 2) void adam_inner(
    const float* __restrict__ Pp, float* __restrict__ out)
{
  __shared__ __align__(16) float hd[4][2][96];   // [wave][buf][h(48)|dh(48)]

  const int lane = threadIdx.x & 63;
  const int wv   = threadIdx.x >> 6;
  const int i    = blockIdx.x * 4 + wv;
  const bool act = lane < NW;

  float* buf0 = &hd[wv][0][0];
  float* buf1 = &hd[wv][1][0];

  float w0  = act ? *pptr(Pp, i, lane)        : 0.f;
  float b0  = act ? *pptr(Pp, i, 48 + lane)   : 0.f;
  float b1v = act ? *pptr(Pp, i, 2400 + lane) : 0.f;
  float b2v = act ? *pptr(Pp, i, 4752 + lane) : 0.f;
  float w3  = act ? *pptr(Pp, i, 4800 + lane) : 0.f;

  f32x2 w1p[24], w2p[24];
  #pragma unroll
  for (int kb = 0; kb < 12; ++kb) {
    float4 q1 = *(const float4*)pptr(Pp, i, 96 + kb * 192 + lane * 4);
    w1p[2 * kb]     = (f32x2){q1.x, q1.y};
    w1p[2 * kb + 1] = (f32x2){q1.z, q1.w};
    float4 q2 = *(const float4*)pptr(Pp, i, 2448 + kb * 192 + lane * 4);
    w2p[2 * kb]     = (f32x2){q2.x, q2.y};
    w2p[2 * kb + 1] = (f32x2){q2.z, q2.w};
  }

  float y = 0.f, m = 0.f, v = 0.f;
  float b1t = 1.f, b2t = 1.f;

  #pragma unroll 1
  for (int t = 0; t < 20; ++t) {
    float z  = fmaf(w0, y, b0);
    float e  = fminf(__expf(-z), 8.0e37f);
    float s  = rcp_nr(1.f + e);
    float h  = z * s;
    float dh = fmaf(z * s, 1.f - s, s) * w0;
    if (act) { buf0[lane] = h; buf0[48 + lane] = dh; }

    f32x2 zz1a = (f32x2){b1v, 0.f}, zz1b = (f32x2){0.f, 0.f};
    f32x2 dd1a = (f32x2){0.f, 0.f}, dd1b = (f32x2){0.f, 0.f};
    #pragma unroll
    for (int kk = 0; kk < 12; ++kk) {
      float4 ph = *(const float4*)(buf0 + 4 * kk);
      float4 pd = *(const float4*)(buf0 + 48 + 4 * kk);
      zz1a = __builtin_elementwise_fma(w1p[2 * kk],     (f32x2){ph.x, ph.y}, zz1a);
      zz1b = __builtin_elementwise_fma(w1p[2 * kk + 1], (f32x2){ph.z, ph.w}, zz1b);
      dd1a = __builtin_elementwise_fma(w1p[2 * kk],     (f32x2){pd.x, pd.y}, dd1a);
      dd1b = __builtin_elementwise_fma(w1p[2 * kk + 1], (f32x2){pd.z, pd.w}, dd1b);
    }
    float z1  = (zz1a.x + zz1a.y) + (zz1b.x + zz1b.y);
    float dz1 = (dd1a.x + dd1a.y) + (dd1b.x + dd1b.y);

    e  = fminf(__expf(-z1), 8.0e37f);
    s  = rcp_nr(1.f + e);
    h  = z1 * s;
    dh = fmaf(z1 * s, 1.f - s, s) * dz1;
    if (act) { buf1[lane] = h; buf1[48 + lane] = dh; }

    f32x2 zz2a = (f32x2){b2v, 0.f}, zz2b = (f32x2){0.f, 0.f};
    f32x2 dd2a = (f32x2){0.f, 0.f}, dd2b = (f32x2){0.f, 0.f};
    #pragma unroll
    for (int kk = 0; kk < 12; ++kk) {
      float4 ph = *(const float4*)(buf1 + 4 * kk);
      float4 pd = *(const float4*)(buf1 + 48 + 4 * kk);
      zz2a = __builtin_elementwise_fma(w2p[2 * kk],     (f32x2){ph.x, ph.y}, zz2a);
      zz2b = __builtin_elementwise_fma(w2p[2 * kk + 1], (f32x2){ph.z, ph.w}, zz2b);
      dd2a = __builtin_elementwise_fma(w2p[2 * kk],     (f32x2){pd.x, pd.y}, dd2a);
      dd2b = __builtin_elementwise_fma(w2p[2 * kk + 1], (f32x2){pd.z, pd.w}, dd2b);
    }
    float z2  = (zz2a.x + zz2a.y) + (zz2b.x + zz2b.y);
    float dz2 = (dd2a.x + dd2a.y) + (dd2b.x + dd2b.y);

    e  = fminf(__expf(-z2), 8.0e37f);
    s  = rcp_nr(1.f + e);
    dh = fmaf(z2 * s, 1.f - s, s) * dz2;

    float tg = act ? w3 * dh : 0.f;
    #pragma unroll
    for (int off = 1; off < 64; off <<= 1) tg += __shfl_xor(tg, off, 64);
    float g = tg;

    m = fmaf(0.9f,   m, 0.1f   * g);
    v = fmaf(0.999f, v, 0.001f * g * g);
    b1t *= 0.9f; b2t *= 0.999f;
    float mh  = m * rcp_nr(1.f - b1t);
    float vh  = v * rcp_nr(1.f - b2t);
    float den = __builtin_amdgcn_sqrtf(vh) + 1e-8f;
    y -= 0.1f * mh * rcp_nr(den);
  }

  if (lane == 0) out[i] = y;
}

// ---------------------------------------------------------------------------
extern "C" void kernel_launch(void* const* d_in, const int* in_sizes, int n_in,
                              void* d_out, int out_size, void* d_ws, size_t ws_size,
                              hipStream_t stream) {
  const float* x   = (const float*)d_in[0];
  const float* c   = (const float*)d_in[1];
  const float* hw1 = (const float*)d_in[2];
  const float* hb1 = (const float*)d_in[3];
  const float* hw2 = (const float*)d_in[4];
  const float* hb2 = (const float*)d_in[5];
  float* Pp  = (float*)d_ws;   // NCH*NB*128*4 = 159,383,552 bytes
  float* out = (float*)d_out;

  dim3 gridB(NCH, GY);         // 38 x 16 persistent blocks
  hyper_gemm<<<gridB, dim3(256), 0, stream>>>(x, c, hw1, hb1, hw2, hb2, Pp);
  adam_inner<<<dim3(2048), dim3(256), 0, stream>>>(Pp, out);
}

// Round 11
// 213.731 us; speedup vs baseline: 1.0931x; 1.0688x over previous
//
#include <hip/hip_runtime.h>
#include <cstdint>
#include <cstddef>

// Problem constants
#define NB    8192      // batch
#define NP    4849      // params per item
#define NW    48        // target net width
#define NCH   38        // ceil(NP/128)
#define GY    16        // persistent-gemm grid y; each block does 128/GY = 8 M-tiles

// Tiled intermediate layout: addr(i, rp) = ((rp>>7)*NB + i)*128 + (rp&127)
typedef __attribute__((ext_vector_type(8))) _Float16 f16x8;
typedef __attribute__((ext_vector_type(4))) float f32x4;
typedef __attribute__((ext_vector_type(2))) float f32x2;

__device__ __forceinline__ const float* pptr(const float* Pp, int i, int rp) {
  return Pp + ((size_t)(rp >> 7) * NB + i) * 128 + (rp & 127);
}

__device__ __forceinline__ int invperm(int rp) {
  if (rp >= 96 && rp < 2400) {
    int t = rp - 96; int kb = t / 192; int rem = t - kb * 192;
    return 96 + (rem >> 2) * 48 + (kb * 4 + (rem & 3));
  }
  if (rp >= 2448 && rp < 4752) {
    int t = rp - 2448; int kb = t / 192; int rem = t - kb * 192;
    return 2448 + (rem >> 2) * 48 + (kb * 4 + (rem & 3));
  }
  return rp;
}

// ---------------------------------------------------------------------------
// Kernel 1: PERSISTENT split-fp16 MFMA GEMM (byte-identical to R10).
// At ~60 us real time this sits at the write roofline for the 163 MB
// intermediate (~2.7 TB/s effective); the remainder of the apparent "110 us"
// is the harness's 159 MB d_ws re-poison memset inside every timed replay.
// ---------------------------------------------------------------------------
__global__ __launch_bounds__(256, 2) void hyper_gemm(
    const float* __restrict__ x, const float* __restrict__ c,
    const float* __restrict__ hw1, const float* __restrict__ hb1,
    const float* __restrict__ hw2, const float* __restrict__ hb2,
    float* __restrict__ Pp)
{
  const int t    = threadIdx.x;
  const int lane = t & 63;
  const int wv   = t >> 6;
  const int m16  = lane & 15;
  const int q    = lane >> 4;
  const int rp0  = blockIdx.x * 128;

  const float* wr[2];
  float bias[2];
  #pragma unroll
  for (int nt = 0; nt < 2; ++nt) {
    int rp = rp0 + wv * 32 + nt * 16 + m16;
    int r  = (rp < NP) ? invperm(rp) : 0;
    wr[nt]   = hw2 + (size_t)r * 96;
    bias[nt] = (rp < NP) ? hb2[r] : 0.f;
  }

  f16x8 bh[3][2], bl[3][2];
  #pragma unroll
  for (int ch = 0; ch < 3; ++ch) {
    const int k0 = ch * 32 + q * 8;
    #pragma unroll
    for (int nt = 0; nt < 2; ++nt) {
      float4 f0 = *(const float4*)(wr[nt] + k0);
      float4 f1 = *(const float4*)(wr[nt] + k0 + 4);
      float fv[8] = {f0.x,f0.y,f0.z,f0.w,f1.x,f1.y,f1.z,f1.w};
      #pragma unroll
      for (int e = 0; e < 8; ++e) {
        _Float16 hi = (_Float16)fv[e];
        float r = fv[e] - (float)hi;
        bh[ch][nt][e] = hi;
        bl[ch][nt][e] = (_Float16)r;
      }
    }
  }

  float* cbase = Pp + (size_t)blockIdx.x * NB * 128;

  for (int mtile = blockIdx.y; mtile < 128; mtile += GY) {
    const int i0 = mtile * 64;

    float xv[4], cv[4];
    #pragma unroll
    for (int mt = 0; mt < 4; ++mt) {
      int i = i0 + mt * 16 + m16;
      xv[mt] = x[i]; cv[mt] = c[i];
    }

    f32x4 acc[4][2];
    #pragma unroll
    for (int mt = 0; mt < 4; ++mt)
      #pragma unroll
      for (int nt = 0; nt < 2; ++nt)
        acc[mt][nt] = (f32x4){0.f, 0.f, 0.f, 0.f};

    #pragma unroll
    for (int ch = 0; ch < 3; ++ch) {
      const int k0 = ch * 32 + q * 8;

      float4 A0 = *(const float4*)(hw1 + 2 * k0);
      float4 A1 = *(const float4*)(hw1 + 2 * k0 + 4);
      float4 A2 = *(const float4*)(hw1 + 2 * k0 + 8);
      float4 A3 = *(const float4*)(hw1 + 2 * k0 + 12);
      float4 B0 = *(const float4*)(hb1 + k0);
      float4 B1 = *(const float4*)(hb1 + k0 + 4);
      float w0k[8] = {A0.x,A0.z,A1.x,A1.z,A2.x,A2.z,A3.x,A3.z};
      float w1k[8] = {A0.y,A0.w,A1.y,A1.w,A2.y,A2.w,A3.y,A3.w};
      float bk[8]  = {B0.x,B0.y,B0.z,B0.w,B1.x,B1.y,B1.z,B1.w};

      f16x8 ah[4], al[4];
      #pragma unroll
      for (int mt = 0; mt < 4; ++mt) {
        #pragma unroll
        for (int j = 0; j < 8; ++j) {
          float h = fmaf(xv[mt], w0k[j], fmaf(cv[mt], w1k[j], bk[j]));
          h = h > 0.f ? h : 0.f;
          _Float16 hi = (_Float16)h;
          float r = h - (float)hi;
          ah[mt][j] = hi;
          al[mt][j] = (_Float16)r;
        }
      }

      #pragma unroll
      for (int mt = 0; mt < 4; ++mt)
        #pragma unroll
        for (int nt = 0; nt < 2; ++nt) {
          acc[mt][nt] = __builtin_amdgcn_mfma_f32_16x16x32_f16(al[mt], bl[ch][nt], acc[mt][nt], 0, 0, 0);
          acc[mt][nt] = __builtin_amdgcn_mfma_f32_16x16x32_f16(ah[mt], bl[ch][nt], acc[mt][nt], 0, 0, 0);
          acc[mt][nt] = __builtin_amdgcn_mfma_f32_16x16x32_f16(al[mt], bh[ch][nt], acc[mt][nt], 0, 0, 0);
          acc[mt][nt] = __builtin_amdgcn_mfma_f32_16x16x32_f16(ah[mt], bh[ch][nt], acc[mt][nt], 0, 0, 0);
        }
    }

    #pragma unroll
    for (int nt = 0; nt < 2; ++nt) {
      int off = wv * 32 + nt * 16 + m16;
      if (rp0 + off < NP) {
        #pragma unroll
        for (int mt = 0; mt < 4; ++mt)
          #pragma unroll
          for (int r = 0; r < 4; ++r) {
            int i = i0 + mt * 16 + q * 4 + r;
            cbase[(size_t)i * 128 + off] = acc[mt][nt][r] + bias[nt];
          }
      }
    }
  }
}

// ---------------------------------------------------------------------------
// Kernel 2 (R11): per-item 20-step Adam on g = f'(y).
// Inferred 3540 cyc/step from R10 counters = two serial latency chains:
// (a) shfl_xor x6 = serial ds_bpermute chain (~600+ cyc) -> replaced with a
//     DPP reduction (VALU pipe: row_shr 1/2/4/8 + row_bcast15/31 + readlane).
// (b) per-layer LDS broadcast reads interleaved with consuming FMAs
//     (~60-100 cyc exposed each x24) -> batch-prefetch ALL 24 float4 reads
//     into registers, then run 8 independent pk_fma chains (depth 6).
// ---------------------------------------------------------------------------
__device__ __forceinline__ float rcp_nr(float d) {
  float r = __builtin_amdgcn_rcpf(d);
  return fmaf(-d, r, 2.f) * r;
}

// x += dpp(x) with add-identity for invalid/masked lanes (LLVM reduce pattern)
#define DPP_ADD(x, ctrl, rmask)                                               \
  (x) += __int_as_float(__builtin_amdgcn_update_dpp(                          \
      0, __float_as_int(x), (ctrl), (rmask), 0xf, false))

__global__ __launch_bounds__(256, 2) void adam_inner(
    const float* __restrict__ Pp, float* __restrict__ out)
{
  __shared__ __align__(16) float hd[4][2][96];   // [wave][buf][h(48)|dh(48)]

  const int lane = threadIdx.x & 63;
  const int wv   = threadIdx.x >> 6;
  const int i    = blockIdx.x * 4 + wv;
  const bool act = lane < NW;

  float* buf0 = &hd[wv][0][0];
  float* buf1 = &hd[wv][1][0];

  float w0  = act ? *pptr(Pp, i, lane)        : 0.f;
  float b0  = act ? *pptr(Pp, i, 48 + lane)   : 0.f;
  float b1v = act ? *pptr(Pp, i, 2400 + lane) : 0.f;
  float b2v = act ? *pptr(Pp, i, 4752 + lane) : 0.f;
  float w3  = act ? *pptr(Pp, i, 4800 + lane) : 0.f;

  f32x2 w1p[24], w2p[24];
  #pragma unroll
  for (int kb = 0; kb < 12; ++kb) {
    float4 q1 = *(const float4*)pptr(Pp, i, 96 + kb * 192 + lane * 4);
    w1p[2 * kb]     = (f32x2){q1.x, q1.y};
    w1p[2 * kb + 1] = (f32x2){q1.z, q1.w};
    float4 q2 = *(const float4*)pptr(Pp, i, 2448 + kb * 192 + lane * 4);
    w2p[2 * kb]     = (f32x2){q2.x, q2.y};
    w2p[2 * kb + 1] = (f32x2){q2.z, q2.w};
  }

  float y = 0.f, m = 0.f, v = 0.f;
  float b1t = 1.f, b2t = 1.f;

  #pragma unroll 1
  for (int t = 0; t < 20; ++t) {
    // ---- layer 0 (scalar input): lane j computes unit j ----
    float z  = fmaf(w0, y, b0);
    float e  = fminf(__expf(-z), 8.0e37f);
    float s  = rcp_nr(1.f + e);
    float h  = z * s;
    float dh = fmaf(z * s, 1.f - s, s) * w0;
    if (act) { buf0[lane] = h; buf0[48 + lane] = dh; }

    // ---- layer 1: prefetch ALL broadcast reads, then 8 indep chains ----
    float4 ph[12], pd[12];
    #pragma unroll
    for (int kk = 0; kk < 12; ++kk) {
      ph[kk] = *(const float4*)(buf0 + 4 * kk);
      pd[kk] = *(const float4*)(buf0 + 48 + 4 * kk);
    }
    {
      f32x2 zz[4] = {(f32x2){b1v, 0.f}, (f32x2){0.f, 0.f},
                     (f32x2){0.f, 0.f}, (f32x2){0.f, 0.f}};
      f32x2 dd[4] = {(f32x2){0.f, 0.f}, (f32x2){0.f, 0.f},
                     (f32x2){0.f, 0.f}, (f32x2){0.f, 0.f}};
      #pragma unroll
      for (int kk = 0; kk < 12; ++kk) {
        int c0 = (2 * kk) & 3, c1 = (2 * kk + 1) & 3;
        zz[c0] = __builtin_elementwise_fma(w1p[2 * kk],     (f32x2){ph[kk].x, ph[kk].y}, zz[c0]);
        zz[c1] = __builtin_elementwise_fma(w1p[2 * kk + 1], (f32x2){ph[kk].z, ph[kk].w}, zz[c1]);
        dd[c0] = __builtin_elementwise_fma(w1p[2 * kk],     (f32x2){pd[kk].x, pd[kk].y}, dd[c0]);
        dd[c1] = __builtin_elementwise_fma(w1p[2 * kk + 1], (f32x2){pd[kk].z, pd[kk].w}, dd[c1]);
      }
      f32x2 zs = (zz[0] + zz[1]) + (zz[2] + zz[3]);
      f32x2 ds = (dd[0] + dd[1]) + (dd[2] + dd[3]);
      float z1  = zs.x + zs.y;
      float dz1 = ds.x + ds.y;

      e  = fminf(__expf(-z1), 8.0e37f);
      s  = rcp_nr(1.f + e);
      h  = z1 * s;
      dh = fmaf(z1 * s, 1.f - s, s) * dz1;
    }
    if (act) { buf1[lane] = h; buf1[48 + lane] = dh; }

    // ---- layer 2 ----
    #pragma unroll
    for (int kk = 0; kk < 12; ++kk) {
      ph[kk] = *(const float4*)(buf1 + 4 * kk);
      pd[kk] = *(const float4*)(buf1 + 48 + 4 * kk);
    }
    {
      f32x2 zz[4] = {(f32x2){b2v, 0.f}, (f32x2){0.f, 0.f},
                     (f32x2){0.f, 0.f}, (f32x2){0.f, 0.f}};
      f32x2 dd[4] = {(f32x2){0.f, 0.f}, (f32x2){0.f, 0.f},
                     (f32x2){0.f, 0.f}, (f32x2){0.f, 0.f}};
      #pragma unroll
      for (int kk = 0; kk < 12; ++kk) {
        int c0 = (2 * kk) & 3, c1 = (2 * kk + 1) & 3;
        zz[c0] = __builtin_elementwise_fma(w2p[2 * kk],     (f32x2){ph[kk].x, ph[kk].y}, zz[c0]);
        zz[c1] = __builtin_elementwise_fma(w2p[2 * kk + 1], (f32x2){ph[kk].z, ph[kk].w}, zz[c1]);
        dd[c0] = __builtin_elementwise_fma(w2p[2 * kk],     (f32x2){pd[kk].x, pd[kk].y}, dd[c0]);
        dd[c1] = __builtin_elementwise_fma(w2p[2 * kk + 1], (f32x2){pd[kk].z, pd[kk].w}, dd[c1]);
      }
      f32x2 zs = (zz[0] + zz[1]) + (zz[2] + zz[3]);
      f32x2 ds = (dd[0] + dd[1]) + (dd[2] + dd[3]);
      float z2  = zs.x + zs.y;
      float dz2 = ds.x + ds.y;

      e  = fminf(__expf(-z2), 8.0e37f);
      s  = rcp_nr(1.f + e);
      dh = fmaf(z2 * s, 1.f - s, s) * dz2;
    }

    // ---- g = w3 . dh3 : DPP reduction (VALU pipe, no DS ops) ----
    float r = act ? w3 * dh : 0.f;
    DPP_ADD(r, 0x111, 0xf);   // row_shr:1
    DPP_ADD(r, 0x112, 0xf);   // row_shr:2
    DPP_ADD(r, 0x114, 0xf);   // row_shr:4
    DPP_ADD(r, 0x118, 0xf);   // row_shr:8  -> lane15 of each row = row sum
    DPP_ADD(r, 0x142, 0xa);   // row_bcast:15 into rows 1,3
    DPP_ADD(r, 0x143, 0xc);   // row_bcast:31 into rows 2,3 -> lane63 = total
    float g = __int_as_float(__builtin_amdgcn_readlane(__float_as_int(r), 63));

    // ---- Adam update (replicated per lane) ----
    m = fmaf(0.9f,   m, 0.1f   * g);
    v = fmaf(0.999f, v, 0.001f * g * g);
    b1t *= 0.9f; b2t *= 0.999f;
    float mh  = m * rcp_nr(1.f - b1t);
    float vh  = v * rcp_nr(1.f - b2t);
    float den = __builtin_amdgcn_sqrtf(vh) + 1e-8f;
    y -= 0.1f * mh * rcp_nr(den);
  }

  if (lane == 0) out[i] = y;
}

// ---------------------------------------------------------------------------
extern "C" void kernel_launch(void* const* d_in, const int* in_sizes, int n_in,
                              void* d_out, int out_size, void* d_ws, size_t ws_size,
                              hipStream_t stream) {
  const float* x   = (const float*)d_in[0];
  const float* c   = (const float*)d_in[1];
  const float* hw1 = (const float*)d_in[2];
  const float* hb1 = (const float*)d_in[3];
  const float* hw2 = (const float*)d_in[4];
  const float* hb2 = (const float*)d_in[5];
  float* Pp  = (float*)d_ws;   // NCH*NB*128*4 = 159,383,552 bytes
  float* out = (float*)d_out;

  dim3 gridB(NCH, GY);         // 38 x 16 persistent blocks
  hyper_gemm<<<gridB, dim3(256), 0, stream>>>(x, c, hw1, hb1, hw2, hb2, Pp);
  adam_inner<<<dim3(2048), dim3(256), 0, stream>>>(Pp, out);
}